// Round 11
// baseline (2322.295 us; speedup 1.0000x reference)
//
#include <hip/hip_runtime.h>
#include <stdint.h>

#define SEQ    512
#define NBATCH 64
#define HID    1024
#define GDIM   4096

typedef __attribute__((ext_vector_type(4))) float          f32x4;
typedef __attribute__((ext_vector_type(8))) short          s16x8;
typedef __attribute__((ext_vector_type(4))) unsigned short u16x4;
typedef __attribute__((ext_vector_type(4))) unsigned int   u32x4;

#define MFMA_BF16(a,b,c) __builtin_amdgcn_mfma_f32_16x16x32_bf16((a),(b),(c),0,0,0)

__device__ __forceinline__ unsigned short f2bf(float f){
  union { float f; unsigned u; } v; v.f = f;
  unsigned r = v.u + 0x7fffu + ((v.u >> 16) & 1u);
  return (unsigned short)(r >> 16);
}

// ---------------- fp32 -> bf16 bulk convert (n4 = elements/4) ----------------
__global__ __launch_bounds__(256) void cvt_bf16(const float* __restrict__ s,
                                                unsigned short* __restrict__ d, int n4){
  int i = blockIdx.x*256 + threadIdx.x;
  if (i >= n4) return;
  f32x4 v = *(const f32x4*)(s + (size_t)i*4);
  u16x4 o;
  o[0]=f2bf(v[0]); o[1]=f2bf(v[1]); o[2]=f2bf(v[2]); o[3]=f2bf(v[3]);
  *(u16x4*)(d + (size_t)i*4) = o;
}

// ---------------- init: h0 -> hring slot 0 (bf16, linear), c0 -> cstate ----
__global__ __launch_bounds__(256) void init_state(const float* __restrict__ h0,
                                                  const float* __restrict__ c0,
                                                  unsigned short* __restrict__ hring,
                                                  float* __restrict__ cstate){
  int i = blockIdx.x*256 + threadIdx.x;   // 65536 total
  hring[i]  = f2bf(h0[i]);
  cstate[i] = c0[i];
}

// ---------------- persistent fused LSTM: xproj GEMM folded into recurrence -----
// 256 blocks x 512 threads = 4 batch-groups (bq: 16 rows) x 64 hidden-groups
// (hg: 16 cols -> 64 gate rows). Wave wv owns K-eighth [128wv,128wv+128).
// Per step t each wave computes BOTH:
//   - h-gate partials for step t   (af from hring via LLC, after flag poll)
//   - xproj partials for step t+1  (ax from bf16 input via L2, no dependency)
// Both reduced through double-buffered LDS partial arrays; epilogue sums
// 8 h-partials + 8 x-partials + bias. No xproj buffer, no separate GEMM.
// Sync protocol = R10 (proven): per-producer monotone flags at LLC, wave
// lanes 0-7 poll their 8 producers, producer tail stores 512B slice ->
// drain -> 1 flag. 2-slot h ring (safety: flag(t+1) follows B2(t) which
// joins all 8 waves whose polls cover all 64 same-bq producers >= t).
// Block swizzle clusters each bq's 64 blocks onto 2 XCDs (x reads L2-local).
__global__ __launch_bounds__(512,1) void lstm_rec(
    const unsigned short* __restrict__ whhb,   // bf16 [4096][1024]
    const unsigned short* __restrict__ wihb,   // bf16 [4096][1024]
    const unsigned short* __restrict__ xbf,    // bf16 [512*64][1024]
    const float* __restrict__ bih, const float* __restrict__ bhh,
    unsigned short* __restrict__ hring,        // bf16 [2][64*1024]
    float* __restrict__ cstate,                // fp32 [64*1024]
    float* __restrict__ outp,                  // fp32 d_out base
    unsigned int* __restrict__ bar,            // [256] flags, stride 32 uints
    int t0, int nsteps)
{
  const int tid = threadIdx.x;
  const int wv = tid >> 6, l = tid & 63;
  const int c16 = l & 15, rq = l >> 4;
  // XCD-clustering swizzle: bid%8 = 2bq+(hg&1) -> bq's blocks on 2 XCDs
  const int m8 = blockIdx.x & 7;
  const int bq = m8 >> 1;                     // batch group 0..3 (16 rows)
  const int hg = ((blockIdx.x >> 3) << 1) | (m8 & 1);   // hidden group 0..63
  const int hc0 = hg * 16;
  const int b0  = bq * 16;
  const int em = tid >> 4, ec = tid & 15;     // epilogue (batch,col), tid<256

  __shared__ float part_h[2*8*16*68];                   // 69.6 KB dbuf
  __shared__ float part_x[2*8*16*68];                   // 69.6 KB dbuf
  __shared__ __align__(16) unsigned short hsh[256];     // 512 B

  // ---- W_hh and W_ih slices -> registers: gate-row local n = nt*16 + c16,
  //      weight row = (n&3)*HID + hc0 + (n>>2); k = wv*128 + ks*32 + rq*8
  s16x8 bhh_r[4][4], bih_r[4][4];
#pragma unroll
  for (int nt = 0; nt < 4; ++nt){
    const int n = nt*16 + c16;
    const size_t grow = (size_t)(n & 3)*HID + hc0 + (n >> 2);
#pragma unroll
    for (int ks = 0; ks < 4; ++ks){
      const size_t off = grow*HID + wv*128 + ks*32 + rq*8;
      bhh_r[nt][ks] = *(const s16x8*)(whhb + off);
      bih_r[nt][ks] = *(const s16x8*)(wihb + off);
    }
  }

  float creg = 0.f, bsum[4] = {0.f,0.f,0.f,0.f};
  if (tid < 256){
    creg = cstate[(size_t)(b0+em)*HID + hc0 + ec];
#pragma unroll
    for (int g = 0; g < 4; ++g){
      const size_t bi = (size_t)g*HID + hc0 + ec;
      bsum[g] = bih[bi] + bhh[bi];
    }
  }

  // this wave's producer flags (lanes 0-7): block (bq, wv*8 + l)
  const unsigned int* fq = bar + ((bq*64 + wv*8 + (l & 7)) << 5);

  // ---- prologue: xproj partials for step t0 -> part_x[t0&1]
  {
    const unsigned short* xb = xbf + ((size_t)t0*NBATCH + b0 + c16)*HID
                             + wv*128 + rq*8;
    s16x8 ax[4];
#pragma unroll
    for (int ks = 0; ks < 4; ++ks)
      ax[ks] = *(const s16x8*)(xb + ks*32);
    f32x4 accx[4];
#pragma unroll
    for (int nt = 0; nt < 4; ++nt) accx[nt] = (f32x4){0.f,0.f,0.f,0.f};
#pragma unroll
    for (int ks = 0; ks < 4; ++ks)
#pragma unroll
      for (int nt = 0; nt < 4; ++nt)
        accx[nt] = MFMA_BF16(ax[ks], bih_r[nt][ks], accx[nt]);
    float* pb = &part_x[(size_t)((t0 & 1)*8 + wv)*16*68];
#pragma unroll
    for (int nt = 0; nt < 4; ++nt)
#pragma unroll
      for (int r = 0; r < 4; ++r)
        pb[(rq*4 + r)*68 + nt*16 + c16] = accx[nt][r];
  }

  for (int t = t0; t < t0 + nsteps; ++t){
    // ---- per-wave poll: lanes 0-7, one producer flag each
    if (l < 8){
      unsigned fv; int spins = 0;
      const unsigned ut = (unsigned)t;
      do {
        asm volatile("global_load_dword %0, %1, off sc0 sc1\n\ts_waitcnt vmcnt(0)"
                     : "=v"(fv) : "v"(fq) : "memory");
        if (fv >= ut) break;
        if (++spins > 2) __builtin_amdgcn_s_sleep(2);
      } while (spins < (1 << 20));
    }

    // ---- issue h fragments (LLC) then x fragments for t+1 (L2 cached)
    const unsigned short* hb = hring + (size_t)(t & 1)*65536
                             + (size_t)(b0 + c16)*HID + wv*128 + rq*8;
    u32x4 af[4];
#define AL(K) asm volatile("global_load_dwordx4 %0, %1, off offset:%c2 sc0 sc1" \
                           : "=v"(af[K]) : "v"(hb), "i"((K)*64))
    AL(0); AL(1); AL(2); AL(3);
#undef AL
    const int tn = (t+1 < SEQ) ? t+1 : SEQ-1;
    const unsigned short* xb = xbf + ((size_t)tn*NBATCH + b0 + c16)*HID
                             + wv*128 + rq*8;
    u32x4 axr[4];
#define XL(K) asm volatile("global_load_dwordx4 %0, %1, off offset:%c2" \
                           : "=v"(axr[K]) : "v"(xb), "i"((K)*64))
    XL(0); XL(1); XL(2); XL(3);
#undef XL
    asm volatile("s_waitcnt vmcnt(4)" ::: "memory");   // af done, axr in flight
    __builtin_amdgcn_sched_barrier(0);

    // ---- MFMA: h-gate partials for step t
    f32x4 acc[4];
#pragma unroll
    for (int nt = 0; nt < 4; ++nt) acc[nt] = (f32x4){0.f,0.f,0.f,0.f};
#pragma unroll
    for (int ks = 0; ks < 4; ++ks){
      const s16x8 a = __builtin_bit_cast(s16x8, af[ks]);
#pragma unroll
      for (int nt = 0; nt < 4; ++nt)
        acc[nt] = MFMA_BF16(a, bhh_r[nt][ks], acc[nt]);
    }
    asm volatile("s_waitcnt vmcnt(0)" ::: "memory");   // axr done
    __builtin_amdgcn_sched_barrier(0);

    // ---- MFMA: xproj partials for step t+1
    f32x4 accx[4];
#pragma unroll
    for (int nt = 0; nt < 4; ++nt) accx[nt] = (f32x4){0.f,0.f,0.f,0.f};
#pragma unroll
    for (int ks = 0; ks < 4; ++ks){
      const s16x8 a = __builtin_bit_cast(s16x8, axr[ks]);
#pragma unroll
      for (int nt = 0; nt < 4; ++nt)
        accx[nt] = MFMA_BF16(a, bih_r[nt][ks], accx[nt]);
    }

    // ---- partials -> LDS: h into buf(t&1), x into buf((t+1)&1)
    {
      float* ph = &part_h[(size_t)(((t   ) & 1)*8 + wv)*16*68];
      float* px = &part_x[(size_t)(((t+1) & 1)*8 + wv)*16*68];
#pragma unroll
      for (int nt = 0; nt < 4; ++nt)
#pragma unroll
        for (int r = 0; r < 4; ++r){
          ph[(rq*4 + r)*68 + nt*16 + c16] = acc[nt][r];
          px[(rq*4 + r)*68 + nt*16 + c16] = accx[nt][r];
        }
    }
    __syncthreads();                                   // B2: partials ready

    // ---- epilogue (256 threads): bias + 8 h-partials + 8 x-partials
    float hval = 0.f;
    const int pbuf = t & 1;
    if (tid < 256){
      f32x4 vv = (f32x4){bsum[0], bsum[1], bsum[2], bsum[3]};
#pragma unroll
      for (int k8 = 0; k8 < 8; ++k8){
        vv += *(const f32x4*)&part_h[((size_t)(pbuf*8 + k8)*16 + em)*68 + ec*4];
        vv += *(const f32x4*)&part_x[((size_t)(pbuf*8 + k8)*16 + em)*68 + ec*4];
      }
      const float ig = 1.f/(1.f + __expf(-vv[0]));
      const float fg = 1.f/(1.f + __expf(-vv[1]));
      const float gg = tanhf(vv[2]);
      const float og = 1.f/(1.f + __expf(-vv[3]));
      creg = fg*creg + ig*gg;
      hval = og * tanhf(creg);
      hsh[em*16 + ec] = f2bf(hval);
    }
    __syncthreads();                                   // B3: hsh ready

    // ---- wave 0 lanes 0-31: store 32 x 16B h chunks -> drain -> flag
    if (tid < 32){
      const int row = l >> 1, ch = l & 1;
      const unsigned short* hp = hring + (size_t)((t+1) & 1)*65536
                               + (size_t)(b0 + row)*HID + hc0 + ch*8;
      u32x4 hv = *(const u32x4*)&hsh[row*16 + ch*8];
      asm volatile("global_store_dwordx4 %0, %1, off sc0 sc1"
                   :: "v"(hp), "v"(hv) : "memory");
      asm volatile("s_waitcnt vmcnt(0)" ::: "memory");
      if (tid == 0){
        unsigned int* fp = bar + ((bq*64 + hg) << 5);
        unsigned int fv = (unsigned int)(t + 1);
        asm volatile("global_store_dword %0, %1, off sc0 sc1"
                     :: "v"(fp), "v"(fv) : "memory");
      }
    }

    // ---- off critical path: outputs, final state
    if (tid < 256){
      const size_t oidx = (size_t)(b0+em)*HID + hc0 + ec;
      outp[(size_t)t*65536 + oidx] = hval;
      if (t == SEQ-1){
        outp[(size_t)SEQ*65536 + oidx]         = hval;   // h_last
        outp[(size_t)SEQ*65536 + 65536 + oidx] = creg;   // c_last
      }
    }
  }

  if (tid < 256)
    cstate[(size_t)(b0+em)*HID + hc0 + ec] = creg;
}

// ---------------------------------------------------------------------------
extern "C" void kernel_launch(void* const* d_in, const int* in_sizes, int n_in,
                              void* d_out, int out_size, void* d_ws, size_t ws_size,
                              hipStream_t stream)
{
  const float* inp = (const float*)d_in[0];
  const float* wih = (const float*)d_in[1];
  const float* whh = (const float*)d_in[2];
  const float* bih = (const float*)d_in[3];
  const float* bhh = (const float*)d_in[4];
  const float* h0  = (const float*)d_in[5];
  const float* c0  = (const float*)d_in[6];
  float* outp = (float*)d_out;

  auto alignup = [](size_t x){ return (x + 255) & ~(size_t)255; };
  char* w = (char*)d_ws;
  unsigned short* in_bf  = (unsigned short*)w; w += alignup((size_t)SEQ*64*1024*2);
  unsigned short* wih_bf = (unsigned short*)w; w += alignup((size_t)4096*1024*2);
  unsigned short* whh_bf = (unsigned short*)w; w += alignup((size_t)4096*1024*2);
  unsigned short* hring  = (unsigned short*)w; w += alignup((size_t)2*64*1024*2);
  float*          cst    = (float*)w;          w += alignup((size_t)64*1024*4);
  unsigned int*   bar    = (unsigned int*)w;

  hipMemsetAsync(bar, 0, 256*32*4, stream);

  cvt_bf16<<<SEQ*64*1024/4/256, 256, 0, stream>>>(inp, in_bf, SEQ*64*1024/4);
  cvt_bf16<<<4096, 256, 0, stream>>>(wih, wih_bf, 4096*1024/4);
  cvt_bf16<<<4096, 256, 0, stream>>>(whh, whh_bf, 4096*1024/4);
  init_state<<<256, 256, 0, stream>>>(h0, c0, hring, cst);

  lstm_rec<<<dim3(256), dim3(512), 0, stream>>>(whh_bf, wih_bf, in_bf, bih, bhh,
                                                hring, cst, outp, bar, 0, SEQ);
}